// Round 3
// baseline (978.968 us; speedup 1.0000x reference)
//
#include <hip/hip_runtime.h>
#include <hip/hip_bf16.h>

#define DD 128
#define LL 8
#define MM 32768
#define NN (LL*MM)
#define GG 5
#define FF 2
#define SORT_STRIDE 33408   // 32768 + 5*128 headroom

typedef __attribute__((ext_vector_type(8))) short short8;
typedef __attribute__((ext_vector_type(4))) short short4v;
typedef __attribute__((ext_vector_type(4))) float f32x4;

#define MFMA16(a,b,c) __builtin_amdgcn_mfma_f32_16x16x32_bf16((a),(b),(c),0,0,0)

__device__ __forceinline__ short f2bf(float x){
  __hip_bfloat16 h = __float2bfloat16(x);
  return *reinterpret_cast<short*>(&h);
}

__device__ __forceinline__ short8 pack8(f32x4 a, f32x4 b){
  short8 r;
  r[0]=f2bf(a[0]); r[1]=f2bf(a[1]); r[2]=f2bf(a[2]); r[3]=f2bf(a[3]);
  r[4]=f2bf(b[0]); r[5]=f2bf(b[1]); r[6]=f2bf(b[2]); r[7]=f2bf(b[3]);
  return r;
}

// ---------------- one-time weight transpose/convert to bf16 [outcol][k] ----
// Fragment-ready: A'-operand of swapped MFMA reads 16B at Wt[col*K + kb + lq*8].
__global__ void prep_kernel(const float* __restrict__ hs_W, const float* __restrict__ W1,
                            const float* __restrict__ W2, const float* __restrict__ W3,
                            const float* __restrict__ Wi,
                            short* __restrict__ hsWt, short* __restrict__ W1t,
                            short* __restrict__ W2t, short* __restrict__ W3t,
                            short* __restrict__ Wit)
{
  int u = blockIdx.x*256 + threadIdx.x;   // 75776 total units of 8 k-elems
  const float* src; short* dst; int ldw;
  if (u < 4096){                                   // hsWt: 128 x 256
    int row=u>>5, k8=u&31;
    src = hs_W + (size_t)(k8<<3)*128 + row; dst = hsWt + row*256 + (k8<<3); ldw=128;
  } else if (u < 24576){                           // W1t: 5 x 128 x 256
    int v=u-4096, g=v>>12, r=v&4095, row=r>>5, k8=r&31;
    src = W1 + (size_t)g*32768 + (size_t)(k8<<3)*128 + row;
    dst = W1t + (size_t)g*32768 + row*256 + (k8<<3); ldw=128;
  } else if (u < 34816){                           // W2t: 5 x 128 x 128
    int v=u-24576, g=v>>11, r=v&2047, row=r>>4, k8=r&15;
    src = W2 + (size_t)g*16384 + (size_t)(k8<<3)*128 + row;
    dst = W2t + (size_t)g*16384 + row*128 + (k8<<3); ldw=128;
  } else if (u < 45056){                           // W3t: 5 x 128 x 128
    int v=u-34816, g=v>>11, r=v&2047, row=r>>4, k8=r&15;
    src = W3 + (size_t)g*16384 + (size_t)(k8<<3)*128 + row;
    dst = W3t + (size_t)g*16384 + row*128 + (k8<<3); ldw=128;
  } else {                                         // Wit: 5 x 384 x 128
    int v=u-45056, g=v/6144, r=v%6144, row=r>>4, k8=r&15;
    src = Wi + (size_t)g*49152 + (size_t)(k8<<3)*384 + row;
    dst = Wit + (size_t)g*49152 + row*128 + (k8<<3); ldw=384;
  }
  short8 o;
#pragma unroll
  for (int j=0;j<8;++j) o[j] = f2bf(src[(size_t)j*ldw]);
  *(short8*)dst = o;
}

// ---------------- bucket sort by gate, per level ----------------
__global__ void count_kernel(const int* __restrict__ gate, int* __restrict__ cnt){
  __shared__ int lc[GG];
  const int li = blockIdx.x >> 7;
  const int m  = ((blockIdx.x & 127) << 8) + threadIdx.x;
  if (threadIdx.x < GG) lc[threadIdx.x] = 0;
  __syncthreads();
  int g = gate[(li+1)*MM + m];
  atomicAdd(&lc[g], 1);
  __syncthreads();
  if (threadIdx.x < GG && lc[threadIdx.x] > 0)
    atomicAdd(&cnt[li*GG + threadIdx.x], lc[threadIdx.x]);
}

__global__ void offs_kernel(const int* __restrict__ cnt, int* __restrict__ off, int* __restrict__ pend){
  int l = threadIdx.x;
  if (l < LL-1){
    int o = 0;
    for (int g = 0; g < GG; ++g){
      off[l*GG+g] = o;
      int c = cnt[l*GG+g];
      pend[l*GG+g] = o + c;
      o += ((c + 127) >> 7) << 7;           // pad each bucket to 128
    }
  }
}

__global__ void scatter_kernel(const int* __restrict__ gate, const int* __restrict__ off,
                               int* __restrict__ cur, int* __restrict__ sorted){
  __shared__ int lc[GG];
  __shared__ int base[GG];
  const int li = blockIdx.x >> 7;
  const int m  = ((blockIdx.x & 127) << 8) + threadIdx.x;
  if (threadIdx.x < GG) lc[threadIdx.x] = 0;
  __syncthreads();
  int g = gate[(li+1)*MM + m];
  int p = atomicAdd(&lc[g], 1);
  __syncthreads();
  if (threadIdx.x < GG)
    base[threadIdx.x] = atomicAdd(&cur[li*GG + threadIdx.x], lc[threadIdx.x]);
  __syncthreads();
  sorted[li*SORT_STRIDE + off[li*GG+g] + base[g] + p] = m;
}

// ---------------- hs = [s|t] @ hs_W + hs_b ----------------
// Swapped operands: A'=hsWt fragment (direct global/L2), B'=input rows.
// No LDS, no barriers. Wave owns 32 rows x 128 cols; epilogue = float4 stores.
__global__ __launch_bounds__(256) void hs_kernel(
    const float* __restrict__ s, const float* __restrict__ t,
    const short* __restrict__ Wt, const float* __restrict__ b,
    float* __restrict__ hs)
{
  const int tid=threadIdx.x, lane=tid&63, w=tid>>6;
  const int l15=lane&15, lq=lane>>4;
  const int row0 = blockIdx.x*128 + w*32;

  f32x4 zf = {0.f,0.f,0.f,0.f};
  f32x4 acc[8][2];
#pragma unroll
  for (int ct=0;ct<8;++ct){ acc[ct][0]=zf; acc[ct][1]=zf; }

  const short* Ab = Wt + l15*256 + (lq<<3);
  for (int kb=0; kb<256; kb+=32){
    const float* base = (kb<128)? s : t;
    const int koff = kb & 127;
    short8 bx[2];
#pragma unroll
    for (int nt=0;nt<2;++nt){
      const float* p = base + (size_t)(row0 + nt*16 + l15)*DD + koff + (lq<<3);
      bx[nt] = pack8(*(const f32x4*)p, *(const f32x4*)(p+4));
    }
#pragma unroll
    for (int ct=0;ct<8;++ct){
      short8 af = *(const short8*)(Ab + ct*4096 + kb);
      acc[ct][0] = MFMA16(af, bx[0], acc[ct][0]);
      acc[ct][1] = MFMA16(af, bx[1], acc[ct][1]);
    }
  }
#pragma unroll
  for (int ct=0;ct<8;++ct){
    f32x4 bv = *(const f32x4*)(b + ct*16 + (lq<<2));
#pragma unroll
    for (int nt=0;nt<2;++nt){
      int row = row0 + nt*16 + l15;
      f32x4 o;
#pragma unroll
      for (int j=0;j<4;++j) o[j] = acc[ct][nt][j] + bv[j];
      *(f32x4*)(hs + (size_t)row*DD + ct*16 + (lq<<2)) = o;
    }
  }
}

// ---------------- fused per-level kernel (swapped-operand, barrier-free) ----
// Block: 64 nodes (128 (node,f) rows), 4 waves x 32 rows. hbuf is wave-private.
__global__ __launch_bounds__(256) void level_kernel(
    int lvl, const float* __restrict__ hsg, float* __restrict__ hfg,
    const int* __restrict__ fanin,
    const short* __restrict__ W1t, const short* __restrict__ W2t,
    const short* __restrict__ W3t, const short* __restrict__ Wit,
    const float* __restrict__ b1, const float* __restrict__ b2,
    const float* __restrict__ b3, const float* __restrict__ bi,
    const float* __restrict__ bh,
    const int* __restrict__ off, const int* __restrict__ pend,
    const int* __restrict__ sorted)
{
  __shared__ __align__(16) short hbuf[128*136];
  __shared__ int nodebuf[64];
  __shared__ int srcbuf[128];
  __shared__ int ginfo;

  const int tid=threadIdx.x, lane=tid&63, w=tid>>6;
  const int l15=lane&15, lq=lane>>4;
  const int li = lvl-1;
  const int pos0 = blockIdx.x*64;

  if (tid==0){
    int g=-1;
    for (int q=0;q<GG;++q)
      if (pos0>=off[li*GG+q] && pos0<pend[li*GG+q]){ g=q; break; }
    ginfo=g;
  }
  if (tid<64) nodebuf[tid] = sorted[li*SORT_STRIDE + pos0 + tid];
  if (tid<128){
    int mg = sorted[li*SORT_STRIDE + pos0 + (tid>>1)];
    srcbuf[tid] = (mg>=0) ? li*MM + fanin[((size_t)li*MM+mg)*FF + (tid&1)] : 0;
  }
  __syncthreads();
  const int g = ginfo;
  if (g<0) return;                 // block-uniform

  const int hrow0 = w*32;
  f32x4 zf = {0.f,0.f,0.f,0.f};

  // ---- GEMM1^T: A'=W1t[g], B'=gathered [hs|hf] rows ----
  f32x4 acc[8][2];
#pragma unroll
  for (int ct=0;ct<8;++ct){ acc[ct][0]=zf; acc[ct][1]=zf; }
  const short* A1 = W1t + (size_t)g*32768 + l15*256 + (lq<<3);
  for (int kb=0;kb<256;kb+=32){
    const float* base = (kb<128)? hsg : hfg;
    const int koff = kb&127;
    short8 bx[2];
#pragma unroll
    for (int nt=0;nt<2;++nt){
      int r = hrow0 + nt*16 + l15;
      const float* p = base + (size_t)srcbuf[r]*DD + koff + (lq<<3);
      bx[nt] = pack8(*(const f32x4*)p, *(const f32x4*)(p+4));
    }
#pragma unroll
    for (int ct=0;ct<8;++ct){
      short8 af = *(const short8*)(A1 + ct*4096 + kb);
      acc[ct][0] = MFMA16(af, bx[0], acc[ct][0]);
      acc[ct][1] = MFMA16(af, bx[1], acc[ct][1]);
    }
  }
#pragma unroll
  for (int ct=0;ct<8;++ct){
    f32x4 bv = *(const f32x4*)(b1 + g*128 + ct*16 + (lq<<2));
#pragma unroll
    for (int nt=0;nt<2;++nt){
      int row = hrow0 + nt*16 + l15;
      short4v pk;
#pragma unroll
      for (int j=0;j<4;++j) pk[j] = f2bf(fmaxf(acc[ct][nt][j] + bv[j], 0.f));
      *(short4v*)(hbuf + row*136 + ct*16 + (lq<<2)) = pk;
    }
  }

  // ---- GEMM2^T: A'=W2t[g], B'=H1 rows from hbuf (wave-private) ----
  f32x4 acc2[8][2];
#pragma unroll
  for (int ct=0;ct<8;++ct){ acc2[ct][0]=zf; acc2[ct][1]=zf; }
  const short* A2 = W2t + (size_t)g*16384 + l15*128 + (lq<<3);
  for (int kb=0;kb<128;kb+=32){
    short8 bx[2];
#pragma unroll
    for (int nt=0;nt<2;++nt)
      bx[nt] = *(const short8*)(hbuf + (hrow0+nt*16+l15)*136 + kb + (lq<<3));
#pragma unroll
    for (int ct=0;ct<8;++ct){
      short8 af = *(const short8*)(A2 + ct*2048 + kb);
      acc2[ct][0] = MFMA16(af, bx[0], acc2[ct][0]);
      acc2[ct][1] = MFMA16(af, bx[1], acc2[ct][1]);
    }
  }
#pragma unroll
  for (int ct=0;ct<8;++ct){
    f32x4 bv = *(const f32x4*)(b2 + g*128 + ct*16 + (lq<<2));
#pragma unroll
    for (int nt=0;nt<2;++nt){
      int row = hrow0 + nt*16 + l15;
      short4v pk;
#pragma unroll
      for (int j=0;j<4;++j) pk[j] = f2bf(fmaxf(acc2[ct][nt][j] + bv[j], 0.f));
      *(short4v*)(hbuf + row*136 + ct*16 + (lq<<2)) = pk;
    }
  }

  // ---- GEMM3^T ----
  f32x4 acc3[8][2];
#pragma unroll
  for (int ct=0;ct<8;++ct){ acc3[ct][0]=zf; acc3[ct][1]=zf; }
  const short* A3 = W3t + (size_t)g*16384 + l15*128 + (lq<<3);
  for (int kb=0;kb<128;kb+=32){
    short8 bx[2];
#pragma unroll
    for (int nt=0;nt<2;++nt)
      bx[nt] = *(const short8*)(hbuf + (hrow0+nt*16+l15)*136 + kb + (lq<<3));
#pragma unroll
    for (int ct=0;ct<8;++ct){
      short8 af = *(const short8*)(A3 + ct*2048 + kb);
      acc3[ct][0] = MFMA16(af, bx[0], acc3[ct][0]);
      acc3[ct][1] = MFMA16(af, bx[1], acc3[ct][1]);
    }
  }
  // msg = pair-sum over F (adjacent lanes) + 2*b3 -> hbuf rows [hrow0, hrow0+16)
#pragma unroll
  for (int ct=0;ct<8;++ct){
    f32x4 bv = *(const f32x4*)(b3 + g*128 + ct*16 + (lq<<2));
#pragma unroll
    for (int nt=0;nt<2;++nt){
      f32x4 mv;
#pragma unroll
      for (int j=0;j<4;++j){
        float v = acc3[ct][nt][j];
        mv[j] = v + __shfl_xor(v, 1) + 2.f*bv[j];
      }
      if ((l15 & 1) == 0){
        int nrow = hrow0 + nt*8 + (l15>>1);
        short4v pk;
#pragma unroll
        for (int j=0;j<4;++j) pk[j] = f2bf(mv[j]);
        *(short4v*)(hbuf + nrow*136 + ct*16 + (lq<<2)) = pk;
      }
    }
  }

  // ---- GRU^T: A'=Wit[g] (384x128), B'=msg rows; h==0 so gh==bh ----
  f32x4 ga[24];
#pragma unroll
  for (int ct=0;ct<24;++ct) ga[ct] = zf;
  const short* AW = Wit + (size_t)g*49152 + l15*128 + (lq<<3);
  short8 bmsg[4];
#pragma unroll
  for (int kb4=0;kb4<4;++kb4)
    bmsg[kb4] = *(const short8*)(hbuf + (hrow0 + l15)*136 + kb4*32 + (lq<<3));
#pragma unroll
  for (int kb4=0;kb4<4;++kb4){
#pragma unroll
    for (int ct=0;ct<24;++ct){
      short8 af = *(const short8*)(AW + ct*2048 + kb4*32);
      ga[ct] = MFMA16(af, bmsg[kb4], ga[ct]);
    }
  }

  // epilogue: lane owns node l15 (4 rows? no: 4 outcol-quads), float4 stores
  int m = nodebuf[w*16 + l15];
  if (m >= 0){
    float* orow = hfg + (size_t)(lvl*MM + m)*DD;
    const float* big = bi + g*384;
    const float* bhg = bh + g*384;
#pragma unroll
    for (int c8=0;c8<8;++c8){
      int dc = c8*16 + (lq<<2);
      f32x4 biR = *(const f32x4*)(big + dc);
      f32x4 biZ = *(const f32x4*)(big + 128 + dc);
      f32x4 biN = *(const f32x4*)(big + 256 + dc);
      f32x4 bhR = *(const f32x4*)(bhg + dc);
      f32x4 bhZ = *(const f32x4*)(bhg + 128 + dc);
      f32x4 bhN = *(const f32x4*)(bhg + 256 + dc);
      f32x4 o;
#pragma unroll
      for (int j=0;j<4;++j){
        float xr = ga[c8][j]    + biR[j] + bhR[j];
        float xz = ga[8+c8][j]  + biZ[j] + bhZ[j];
        float r_ = 1.f/(1.f + __expf(-xr));
        float z_ = 1.f/(1.f + __expf(-xz));
        float xn = ga[16+c8][j] + biN[j] + r_*bhN[j];
        float n_ = 2.f/(1.f + __expf(-2.f*xn)) - 1.f;
        o[j] = (1.f - z_)*n_;
      }
      *(f32x4*)(orow + dc) = o;
    }
  }
}

extern "C" void kernel_launch(void* const* d_in, const int* in_sizes, int n_in,
                              void* d_out, int out_size, void* d_ws, size_t ws_size,
                              hipStream_t stream)
{
  const float* s    = (const float*)d_in[0];
  const float* t    = (const float*)d_in[1];
  const int*   gate = (const int*)d_in[2];
  const int*   fanin= (const int*)d_in[3];
  const float* hs_W = (const float*)d_in[4];
  const float* hs_b = (const float*)d_in[5];
  const float* W1   = (const float*)d_in[6];
  const float* b1   = (const float*)d_in[7];
  const float* W2   = (const float*)d_in[8];
  const float* b2   = (const float*)d_in[9];
  const float* W3   = (const float*)d_in[10];
  const float* b3   = (const float*)d_in[11];
  const float* Wi   = (const float*)d_in[12];
  // d_in[13] = gru_Wh: unused (hidden state is exactly zero)
  const float* bi   = (const float*)d_in[14];
  const float* bh   = (const float*)d_in[15];

  float* hs = (float*)d_out;
  float* hf = hs + (size_t)NN*DD;

  int* cnt    = (int*)d_ws;        // [7][5]
  int* cur    = cnt + 35;
  int* off    = cnt + 70;
  int* pendv  = cnt + 105;
  int* sorted = cnt + 256;         // 7*SORT_STRIDE ints, ends < 1 MB

  short* wbase = (short*)((char*)d_ws + (1<<20));
  short* hsWt = wbase;             // 128*256
  short* W1t  = wbase + 32768;     // 5*128*256
  short* W2t  = wbase + 196608;    // 5*128*128
  short* W3t  = wbase + 278528;    // 5*128*128
  short* Wit  = wbase + 360448;    // 5*384*128  (ends at ~2.26 MB into ws)

  hipMemsetAsync(cnt, 0, 70*sizeof(int), stream);
  hipMemsetAsync(sorted, 0xFF, (size_t)(LL-1)*SORT_STRIDE*sizeof(int), stream);
  hipMemsetAsync(hf, 0, (size_t)MM*DD*sizeof(float), stream);   // level-0 hf stays zero

  prep_kernel<<<296, 256, 0, stream>>>(hs_W, W1, W2, W3, Wi, hsWt, W1t, W2t, W3t, Wit);
  count_kernel<<<896, 256, 0, stream>>>(gate, cnt);
  offs_kernel<<<1, 64, 0, stream>>>(cnt, off, pendv);
  scatter_kernel<<<896, 256, 0, stream>>>(gate, off, cur, sorted);
  hs_kernel<<<NN/128, 256, 0, stream>>>(s, t, hsWt, hs_b, hs);
  for (int lvl = 1; lvl < LL; ++lvl){
    level_kernel<<<SORT_STRIDE/64, 256, 0, stream>>>(lvl, hs, hf, fanin,
        W1t, W2t, W3t, Wit, b1, b2, b3, bi, bh, off, pendv, sorted);
  }
}

// Round 4
// 517.084 us; speedup vs baseline: 1.8932x; 1.8932x over previous
//
#include <hip/hip_runtime.h>
#include <hip/hip_bf16.h>

#define DD 128
#define LL 8
#define MM 32768
#define NN (LL*MM)
#define GG 5
#define FF 2
#define SORT_STRIDE 33408   // 32768 + 5*128 headroom

typedef __attribute__((ext_vector_type(8))) short short8;
typedef __attribute__((ext_vector_type(4))) short short4v;
typedef __attribute__((ext_vector_type(4))) float f32x4;

#define MFMA16(a,b,c) __builtin_amdgcn_mfma_f32_16x16x32_bf16((a),(b),(c),0,0,0)

__device__ __forceinline__ short f2bf(float x){
  __hip_bfloat16 h = __float2bfloat16(x);
  return *reinterpret_cast<short*>(&h);
}

__device__ __forceinline__ short8 pack8(f32x4 a, f32x4 b){
  short8 r;
  r[0]=f2bf(a[0]); r[1]=f2bf(a[1]); r[2]=f2bf(a[2]); r[3]=f2bf(a[3]);
  r[4]=f2bf(b[0]); r[5]=f2bf(b[1]); r[6]=f2bf(b[2]); r[7]=f2bf(b[3]);
  return r;
}

// ---------------- one-time weight transpose/convert to bf16 [outcol][k] ----
__global__ void prep_kernel(const float* __restrict__ hs_W, const float* __restrict__ W1,
                            const float* __restrict__ W2, const float* __restrict__ W3,
                            const float* __restrict__ Wi,
                            short* __restrict__ hsWt, short* __restrict__ W1t,
                            short* __restrict__ W2t, short* __restrict__ W3t,
                            short* __restrict__ Wit)
{
  int u = blockIdx.x*256 + threadIdx.x;   // 75776 units of 8 k-elems
  const float* src; short* dst; int ldw;
  if (u < 4096){                                   // hsWt: 128 x 256
    int row=u>>5, k8=u&31;
    src = hs_W + (size_t)(k8<<3)*128 + row; dst = hsWt + row*256 + (k8<<3); ldw=128;
  } else if (u < 24576){                           // W1t: 5 x 128 x 256
    int v=u-4096, g=v>>12, r=v&4095, row=r>>5, k8=r&31;
    src = W1 + (size_t)g*32768 + (size_t)(k8<<3)*128 + row;
    dst = W1t + (size_t)g*32768 + row*256 + (k8<<3); ldw=128;
  } else if (u < 34816){                           // W2t: 5 x 128 x 128
    int v=u-24576, g=v>>11, r=v&2047, row=r>>4, k8=r&15;
    src = W2 + (size_t)g*16384 + (size_t)(k8<<3)*128 + row;
    dst = W2t + (size_t)g*16384 + row*128 + (k8<<3); ldw=128;
  } else if (u < 45056){                           // W3t: 5 x 128 x 128
    int v=u-34816, g=v>>11, r=v&2047, row=r>>4, k8=r&15;
    src = W3 + (size_t)g*16384 + (size_t)(k8<<3)*128 + row;
    dst = W3t + (size_t)g*16384 + row*128 + (k8<<3); ldw=128;
  } else {                                         // Wit: 5 x 384 x 128
    int v=u-45056, g=v/6144, r=v%6144, row=r>>4, k8=r&15;
    src = Wi + (size_t)g*49152 + (size_t)(k8<<3)*384 + row;
    dst = Wit + (size_t)g*49152 + row*128 + (k8<<3); ldw=384;
  }
  short8 o;
#pragma unroll
  for (int j=0;j<8;++j) o[j] = f2bf(src[(size_t)j*ldw]);
  *(short8*)dst = o;
}

// ---------------- bucket sort by gate, per level ----------------
__global__ void count_kernel(const int* __restrict__ gate, int* __restrict__ cnt){
  __shared__ int lc[GG];
  const int li = blockIdx.x >> 7;
  const int m  = ((blockIdx.x & 127) << 8) + threadIdx.x;
  if (threadIdx.x < GG) lc[threadIdx.x] = 0;
  __syncthreads();
  int g = gate[(li+1)*MM + m];
  atomicAdd(&lc[g], 1);
  __syncthreads();
  if (threadIdx.x < GG && lc[threadIdx.x] > 0)
    atomicAdd(&cnt[li*GG + threadIdx.x], lc[threadIdx.x]);
}

__global__ void offs_kernel(const int* __restrict__ cnt, int* __restrict__ off, int* __restrict__ pend){
  int l = threadIdx.x;
  if (l < LL-1){
    int o = 0;
    for (int g = 0; g < GG; ++g){
      off[l*GG+g] = o;
      int c = cnt[l*GG+g];
      pend[l*GG+g] = o + c;
      o += ((c + 127) >> 7) << 7;           // pad each bucket to 128
    }
  }
}

__global__ void scatter_kernel(const int* __restrict__ gate, const int* __restrict__ off,
                               int* __restrict__ cur, int* __restrict__ sorted){
  __shared__ int lc[GG];
  __shared__ int base[GG];
  const int li = blockIdx.x >> 7;
  const int m  = ((blockIdx.x & 127) << 8) + threadIdx.x;
  if (threadIdx.x < GG) lc[threadIdx.x] = 0;
  __syncthreads();
  int g = gate[(li+1)*MM + m];
  int p = atomicAdd(&lc[g], 1);
  __syncthreads();
  if (threadIdx.x < GG)
    base[threadIdx.x] = atomicAdd(&cur[li*GG + threadIdx.x], lc[threadIdx.x]);
  __syncthreads();
  sorted[li*SORT_STRIDE + off[li*GG+g] + base[g] + p] = m;
}

// ---------------- hs = [s|t] @ hs_W + hs_b ----------------
// 8 waves, wave tile 64 rows x 32 cols. X staged in fragment-layout LDS:
// slot(rf,kc,lane) = X[row=rf*16+(l&15)][k=kc*32+8*(l>>4)..+8] -> linear-in-lane b128 reads.
__global__ __launch_bounds__(512,4) void hs_kernel(
    const float* __restrict__ s, const float* __restrict__ t,
    const short* __restrict__ Wt, const float* __restrict__ b,
    float* __restrict__ hs, short* __restrict__ hs_sh)
{
  __shared__ __align__(16) short Xs[32768];
  const int tid=threadIdx.x, lane=tid&63, w=tid>>6;
  const int l15=lane&15, lq=lane>>4;
  const int wr=w>>2, wc=w&3;
  const int row0 = blockIdx.x*128;

  // stage: thread (r,p) handles 8 units of 8 k-elems
  {
    const int r = tid>>2, p = tid&3;
    const float* srow = s + (size_t)(row0+r)*DD;
    const float* trow = t + (size_t)(row0+r)*DD;
    const int rf = r>>4, rl = r&15;
#pragma unroll
    for (int i=0;i<8;++i){
      int u = p + 4*i;
      const float* pp = (u<16) ? (srow + 8*u) : (trow + 8*(u-16));
      short8 v = pack8(*(const f32x4*)pp, *(const f32x4*)(pp+4));
      *(short8*)(Xs + ((rf*8+(u>>2))*64 + (u&3)*16 + rl)*8) = v;
    }
  }
  __syncthreads();

  f32x4 zf = {0.f,0.f,0.f,0.f};
  f32x4 acc[4][2];
#pragma unroll
  for (int rr=0;rr<4;++rr){ acc[rr][0]=zf; acc[rr][1]=zf; }

  const short* A1 = Wt + (32*wc + l15)*256 + 8*lq;   // ct=2wc ; +16*256 for ct=2wc+1
#pragma unroll
  for (int kc=0;kc<8;++kc){
    short8 a0 = *(const short8*)(A1 + kc*32);
    short8 a1 = *(const short8*)(A1 + 16*256 + kc*32);
#pragma unroll
    for (int rr=0;rr<4;++rr){
      short8 bx = *(const short8*)(Xs + (((4*wr+rr)*8 + kc)*64 + lane)*8);
      acc[rr][0] = MFMA16(a0, bx, acc[rr][0]);
      acc[rr][1] = MFMA16(a1, bx, acc[rr][1]);
    }
  }

  f32x4 bv0 = *(const f32x4*)(b + 32*wc + 4*lq);
  f32x4 bv1 = *(const f32x4*)(b + 32*wc + 16 + 4*lq);
#pragma unroll
  for (int rr=0;rr<4;++rr){
    int row = row0 + (4*wr+rr)*16 + l15;
#pragma unroll
    for (int q=0;q<2;++q){
      f32x4 bv = q ? bv1 : bv0;
      int col = 32*wc + 16*q + 4*lq;
      f32x4 o; short4v pk;
#pragma unroll
      for (int j=0;j<4;++j){ o[j] = acc[rr][q][j] + bv[j]; pk[j] = f2bf(o[j]); }
      *(f32x4*)(hs + (size_t)row*DD + col) = o;
      *(short4v*)(hs_sh + (size_t)row*DD + col) = pk;
    }
  }
}

// ---------------- fused per-level kernel ----------------
// 8 waves x (64 rows x 32 cols). X(64KB) -> GEMM1 -> H1 (overlay X[0:16K])
// -> GEMM2 -> H2 (X[16K:32K]) -> GEMM3 -> pair-sum -> msg (X[0:8K]) -> GRU.
__global__ __launch_bounds__(512,4) void level_kernel(
    int lvl, float* __restrict__ hfg,
    const short* __restrict__ hs_sh, short* __restrict__ hf_sh,
    const int* __restrict__ fanin,
    const short* __restrict__ W1t, const short* __restrict__ W2t,
    const short* __restrict__ W3t, const short* __restrict__ Wit,
    const float* __restrict__ b1, const float* __restrict__ b2,
    const float* __restrict__ b3, const float* __restrict__ bi,
    const float* __restrict__ bh,
    const int* __restrict__ off, const int* __restrict__ pend,
    const int* __restrict__ sorted)
{
  __shared__ __align__(16) short Xs[32768];
  __shared__ int nodebuf[64];
  __shared__ int srcbuf[128];
  __shared__ int ginfo;

  const int tid=threadIdx.x, lane=tid&63, w=tid>>6;
  const int l15=lane&15, lq=lane>>4;
  const int wr=w>>2, wc=w&3;
  const int li = lvl-1;
  const int pos0 = blockIdx.x*64;

  if (tid==0){
    int g=-1;
    for (int q=0;q<GG;++q)
      if (pos0>=off[li*GG+q] && pos0<pend[li*GG+q]){ g=q; break; }
    ginfo=g;
  }
  if (tid<64) nodebuf[tid] = sorted[li*SORT_STRIDE + pos0 + tid];
  if (tid<128){
    int mg = sorted[li*SORT_STRIDE + pos0 + (tid>>1)];
    srcbuf[tid] = (mg>=0) ? li*MM + fanin[((size_t)li*MM+mg)*FF + (tid&1)] : 0;
  }
  __syncthreads();                                  // B0
  const int g = ginfo;
  if (g<0) return;                                  // block-uniform

  // gather X = [hs_sh|hf_sh][src] rows into fragment layout
  {
    const int r = tid>>2, p = tid&3;
    const int src = srcbuf[r];
    const short* hsrow = hs_sh + (size_t)src*DD;
    const short* hfrow = hf_sh + (size_t)src*DD;
    const int rf = r>>4, rl = r&15;
#pragma unroll
    for (int i=0;i<8;++i){
      int u = p + 4*i;
      short8 v = *(const short8*)((u<16) ? (hsrow + 8*u) : (hfrow + 8*(u-16)));
      *(short8*)(Xs + ((rf*8+(u>>2))*64 + (u&3)*16 + rl)*8) = v;
    }
  }
  __syncthreads();                                  // B1

  f32x4 zf = {0.f,0.f,0.f,0.f};

  // ---- GEMM1: K=256 ----
  f32x4 acc[4][2];
#pragma unroll
  for (int rr=0;rr<4;++rr){ acc[rr][0]=zf; acc[rr][1]=zf; }
  const short* A1 = W1t + (size_t)g*32768 + (32*wc + l15)*256 + 8*lq;
#pragma unroll
  for (int kc=0;kc<8;++kc){
    short8 a0 = *(const short8*)(A1 + kc*32);
    short8 a1 = *(const short8*)(A1 + 16*256 + kc*32);
#pragma unroll
    for (int rr=0;rr<4;++rr){
      short8 bx = *(const short8*)(Xs + (((4*wr+rr)*8 + kc)*64 + lane)*8);
      acc[rr][0] = MFMA16(a0, bx, acc[rr][0]);
      acc[rr][1] = MFMA16(a1, bx, acc[rr][1]);
    }
  }
  __syncthreads();                                  // B2: all X reads done
  {
    f32x4 bv0 = *(const f32x4*)(b1 + g*DD + 32*wc + 4*lq);
    f32x4 bv1 = *(const f32x4*)(b1 + g*DD + 32*wc + 16 + 4*lq);
#pragma unroll
    for (int rr=0;rr<4;++rr){
      int rf = 4*wr + rr;
#pragma unroll
      for (int q=0;q<2;++q){
        f32x4 bv = q ? bv1 : bv0;
        short4v pk;
#pragma unroll
        for (int j=0;j<4;++j) pk[j] = f2bf(fmaxf(acc[rr][q][j] + bv[j], 0.f));
        *(short4v*)(Xs + ((rf*4 + wc)*64 + (2*q + (lq>>1))*16 + l15)*8 + 4*(lq&1)) = pk;
      }
    }
  }
  __syncthreads();                                  // B3: H1 ready

  // ---- GEMM2: K=128, B from H1 (Xs[0:16384]) ----
  f32x4 acc2[4][2];
#pragma unroll
  for (int rr=0;rr<4;++rr){ acc2[rr][0]=zf; acc2[rr][1]=zf; }
  const short* A2 = W2t + (size_t)g*16384 + (32*wc + l15)*128 + 8*lq;
#pragma unroll
  for (int kc=0;kc<4;++kc){
    short8 a0 = *(const short8*)(A2 + kc*32);
    short8 a1 = *(const short8*)(A2 + 16*128 + kc*32);
#pragma unroll
    for (int rr=0;rr<4;++rr){
      short8 bx = *(const short8*)(Xs + (((4*wr+rr)*4 + kc)*64 + lane)*8);
      acc2[rr][0] = MFMA16(a0, bx, acc2[rr][0]);
      acc2[rr][1] = MFMA16(a1, bx, acc2[rr][1]);
    }
  }
  // H2 into Xs[16384:32768] (X upper half: dead since B2)
  {
    f32x4 bv0 = *(const f32x4*)(b2 + g*DD + 32*wc + 4*lq);
    f32x4 bv1 = *(const f32x4*)(b2 + g*DD + 32*wc + 16 + 4*lq);
#pragma unroll
    for (int rr=0;rr<4;++rr){
      int rf = 4*wr + rr;
#pragma unroll
      for (int q=0;q<2;++q){
        f32x4 bv = q ? bv1 : bv0;
        short4v pk;
#pragma unroll
        for (int j=0;j<4;++j) pk[j] = f2bf(fmaxf(acc2[rr][q][j] + bv[j], 0.f));
        *(short4v*)(Xs + 16384 + ((rf*4 + wc)*64 + (2*q + (lq>>1))*16 + l15)*8 + 4*(lq&1)) = pk;
      }
    }
  }
  __syncthreads();                                  // B4: H2 ready, H1 reads done

  // ---- GEMM3: K=128, B from H2 ----
  f32x4 acc3[4][2];
#pragma unroll
  for (int rr=0;rr<4;++rr){ acc3[rr][0]=zf; acc3[rr][1]=zf; }
  const short* A3 = W3t + (size_t)g*16384 + (32*wc + l15)*128 + 8*lq;
#pragma unroll
  for (int kc=0;kc<4;++kc){
    short8 a0 = *(const short8*)(A3 + kc*32);
    short8 a1 = *(const short8*)(A3 + 16*128 + kc*32);
#pragma unroll
    for (int rr=0;rr<4;++rr){
      short8 bx = *(const short8*)(Xs + 16384 + (((4*wr+rr)*4 + kc)*64 + lane)*8);
      acc3[rr][0] = MFMA16(a0, bx, acc3[rr][0]);
      acc3[rr][1] = MFMA16(a1, bx, acc3[rr][1]);
    }
  }
  // pair-sum over F (adjacent l15 lanes) -> msg into Xs[0:8192] (H1 dead)
  {
    f32x4 bv0 = *(const f32x4*)(b3 + g*DD + 32*wc + 4*lq);
    f32x4 bv1 = *(const f32x4*)(b3 + g*DD + 32*wc + 16 + 4*lq);
#pragma unroll
    for (int rr=0;rr<4;++rr){
#pragma unroll
      for (int q=0;q<2;++q){
        f32x4 bv = q ? bv1 : bv0;
        f32x4 mv;
#pragma unroll
        for (int j=0;j<4;++j){
          float v = acc3[rr][q][j];
          mv[j] = v + __shfl_xor(v, 1) + 2.f*bv[j];
        }
        if ((l15 & 1) == 0){
          int n = (4*wr+rr)*8 + (l15>>1);          // node 0..63
          short4v pk;
#pragma unroll
          for (int j=0;j<4;++j) pk[j] = f2bf(mv[j]);
          *(short4v*)(Xs + (((n>>4)*4 + wc)*64 + (2*q + (lq>>1))*16 + (n&15))*8 + 4*(lq&1)) = pk;
        }
      }
    }
  }
  __syncthreads();                                  // B5: msg ready

  // ---- GRU: gi = msg(64x128) @ Wi[g]; h==0 so gh==bh. Wave w: cols {16w..}+{0,128,256} ----
  f32x4 gr[4], gz[4], gn[4];
#pragma unroll
  for (int rfm=0;rfm<4;++rfm){ gr[rfm]=zf; gz[rfm]=zf; gn[rfm]=zf; }
  const short* AW = Wit + (size_t)g*49152 + (16*w + l15)*128 + 8*lq;
#pragma unroll
  for (int kc=0;kc<4;++kc){
    short8 aR = *(const short8*)(AW + kc*32);
    short8 aZ = *(const short8*)(AW + 16384 + kc*32);
    short8 aN = *(const short8*)(AW + 32768 + kc*32);
#pragma unroll
    for (int rfm=0;rfm<4;++rfm){
      short8 bm = *(const short8*)(Xs + ((rfm*4 + kc)*64 + lane)*8);
      gr[rfm] = MFMA16(aR, bm, gr[rfm]);
      gz[rfm] = MFMA16(aZ, bm, gz[rfm]);
      gn[rfm] = MFMA16(aN, bm, gn[rfm]);
    }
  }

  const int lo = lvl*MM;
  f32x4 biR = *(const f32x4*)(bi + g*384 + 16*w + 4*lq);
  f32x4 biZ = *(const f32x4*)(bi + g*384 + 128 + 16*w + 4*lq);
  f32x4 biN = *(const f32x4*)(bi + g*384 + 256 + 16*w + 4*lq);
  f32x4 bhR = *(const f32x4*)(bh + g*384 + 16*w + 4*lq);
  f32x4 bhZ = *(const f32x4*)(bh + g*384 + 128 + 16*w + 4*lq);
  f32x4 bhN = *(const f32x4*)(bh + g*384 + 256 + 16*w + 4*lq);
#pragma unroll
  for (int rfm=0;rfm<4;++rfm){
    int m = nodebuf[rfm*16 + l15];
    if (m < 0) continue;
    f32x4 o; short4v pk;
#pragma unroll
    for (int j=0;j<4;++j){
      float xr = gr[rfm][j] + biR[j] + bhR[j];
      float xz = gz[rfm][j] + biZ[j] + bhZ[j];
      float r_ = 1.f/(1.f + __expf(-xr));
      float z_ = 1.f/(1.f + __expf(-xz));
      float xn = gn[rfm][j] + biN[j] + r_*bhN[j];
      float n_ = 2.f/(1.f + __expf(-2.f*xn)) - 1.f;
      o[j] = (1.f - z_)*n_;
      pk[j] = f2bf(o[j]);
    }
    int col = 16*w + 4*lq;
    *(f32x4*)(hfg + (size_t)(lo + m)*DD + col) = o;
    *(short4v*)(hf_sh + (size_t)(lo + m)*DD + col) = pk;
  }
}

extern "C" void kernel_launch(void* const* d_in, const int* in_sizes, int n_in,
                              void* d_out, int out_size, void* d_ws, size_t ws_size,
                              hipStream_t stream)
{
  const float* s    = (const float*)d_in[0];
  const float* t    = (const float*)d_in[1];
  const int*   gate = (const int*)d_in[2];
  const int*   fanin= (const int*)d_in[3];
  const float* hs_W = (const float*)d_in[4];
  const float* hs_b = (const float*)d_in[5];
  const float* W1   = (const float*)d_in[6];
  const float* b1   = (const float*)d_in[7];
  const float* W2   = (const float*)d_in[8];
  const float* b2   = (const float*)d_in[9];
  const float* W3   = (const float*)d_in[10];
  const float* b3   = (const float*)d_in[11];
  const float* Wi   = (const float*)d_in[12];
  // d_in[13] = gru_Wh: unused (hidden state is exactly zero)
  const float* bi   = (const float*)d_in[14];
  const float* bh   = (const float*)d_in[15];

  float* hs = (float*)d_out;
  float* hf = hs + (size_t)NN*DD;

  int* cnt    = (int*)d_ws;        // [7][5]
  int* cur    = cnt + 35;
  int* off    = cnt + 70;
  int* pendv  = cnt + 105;
  int* sorted = cnt + 256;         // 7*SORT_STRIDE ints, < 1 MB

  short* wbase = (short*)((char*)d_ws + (1<<20));
  short* hsWt = wbase;             // 128*256
  short* W1t  = wbase + 32768;     // 5*128*256
  short* W2t  = wbase + 196608;    // 5*128*128
  short* W3t  = wbase + 278528;    // 5*128*128
  short* Wit  = wbase + 360448;    // 5*384*128

  short* hs_sh = (short*)((char*)d_ws + (size_t)(8<<20));   // [N][128] bf16, 64MB
  short* hf_sh = hs_sh + (size_t)NN*DD;                      // [N][128] bf16, 64MB

  hipMemsetAsync(cnt, 0, 70*sizeof(int), stream);
  hipMemsetAsync(sorted, 0xFF, (size_t)(LL-1)*SORT_STRIDE*sizeof(int), stream);
  hipMemsetAsync(hf, 0, (size_t)MM*DD*sizeof(float), stream);   // level-0 hf f32 output = 0
  hipMemsetAsync(hf_sh, 0, (size_t)MM*DD*sizeof(short), stream);// level-0 hf shadow = 0

  prep_kernel<<<296, 256, 0, stream>>>(hs_W, W1, W2, W3, Wi, hsWt, W1t, W2t, W3t, Wit);
  count_kernel<<<896, 256, 0, stream>>>(gate, cnt);
  offs_kernel<<<1, 64, 0, stream>>>(cnt, off, pendv);
  scatter_kernel<<<896, 256, 0, stream>>>(gate, off, cur, sorted);
  hs_kernel<<<NN/128, 512, 0, stream>>>(s, t, hsWt, hs_b, hs, hs_sh);
  for (int lvl = 1; lvl < LL; ++lvl){
    level_kernel<<<SORT_STRIDE/64, 512, 0, stream>>>(lvl, hf,
        hs_sh, hf_sh, fanin, W1t, W2t, W3t, Wit,
        b1, b2, b3, bi, bh, off, pendv, sorted);
  }
}

// Round 5
// 414.140 us; speedup vs baseline: 2.3639x; 1.2486x over previous
//
#include <hip/hip_runtime.h>
#include <hip/hip_bf16.h>

#define DD 128
#define LL 8
#define MM 32768
#define NN (LL*MM)
#define GG 5
#define FF 2
#define SORT_STRIDE 33408   // 32768 + 5*128 headroom

typedef __attribute__((ext_vector_type(8))) short short8;
typedef __attribute__((ext_vector_type(4))) short short4v;
typedef __attribute__((ext_vector_type(4))) float f32x4;

#define MFMA16(a,b,c) __builtin_amdgcn_mfma_f32_16x16x32_bf16((a),(b),(c),0,0,0)

__device__ __forceinline__ short f2bf(float x){
  __hip_bfloat16 h = __float2bfloat16(x);
  return *reinterpret_cast<short*>(&h);
}

__device__ __forceinline__ short8 pack8(f32x4 a, f32x4 b){
  short8 r;
  r[0]=f2bf(a[0]); r[1]=f2bf(a[1]); r[2]=f2bf(a[2]); r[3]=f2bf(a[3]);
  r[4]=f2bf(b[0]); r[5]=f2bf(b[1]); r[6]=f2bf(b[2]); r[7]=f2bf(b[3]);
  return r;
}

// ---------------- one-time weight convert to fragment-contiguous bf16 ------
// Layout per tensor: [g][ct][kc][lane][8]  (ct = 16-col tile, kc = 32-k tile)
// value[j] = W[k = kc*32 + 8*(lane>>4) + j][col = ct*16 + (lane&15)]
// -> a wave's A-fragment load is ONE contiguous 1KB transaction.
__global__ void prep_kernel(const float* __restrict__ hs_W, const float* __restrict__ W1,
                            const float* __restrict__ W2, const float* __restrict__ W3,
                            const float* __restrict__ Wi,
                            short* __restrict__ hsWt, short* __restrict__ W1t,
                            short* __restrict__ W2t, short* __restrict__ W3t,
                            short* __restrict__ Wit, int* __restrict__ cntcur)
{
  if (blockIdx.x == 0 && threadIdx.x < 70) cntcur[threadIdx.x] = 0;  // cnt[35]+cur[35]
  int u = blockIdx.x*256 + threadIdx.x;   // 75776 units of 8 k-elems
  const float* src; short* dst; int ldw;
  if (u < 4096){                                   // hsWt: ct8 kc8
    int i=u, ct=i>>9, kc=(i>>6)&7, lane=i&63;
    src = hs_W + (size_t)(kc*32 + 8*(lane>>4))*128 + ct*16 + (lane&15);
    dst = hsWt + (size_t)i*8; ldw=128;
  } else if (u < 24576){                           // W1t: 5 x (ct8 kc8)
    int v=u-4096, g=v>>12, i=v&4095, ct=i>>9, kc=(i>>6)&7, lane=i&63;
    src = W1 + (size_t)g*32768 + (size_t)(kc*32 + 8*(lane>>4))*128 + ct*16 + (lane&15);
    dst = W1t + (size_t)g*32768 + i*8; ldw=128;
  } else if (u < 34816){                           // W2t: 5 x (ct8 kc4)
    int v=u-24576, g=v>>11, i=v&2047, ct=i>>8, kc=(i>>6)&3, lane=i&63;
    src = W2 + (size_t)g*16384 + (size_t)(kc*32 + 8*(lane>>4))*128 + ct*16 + (lane&15);
    dst = W2t + (size_t)g*16384 + i*8; ldw=128;
  } else if (u < 45056){                           // W3t: 5 x (ct8 kc4)
    int v=u-34816, g=v>>11, i=v&2047, ct=i>>8, kc=(i>>6)&3, lane=i&63;
    src = W3 + (size_t)g*16384 + (size_t)(kc*32 + 8*(lane>>4))*128 + ct*16 + (lane&15);
    dst = W3t + (size_t)g*16384 + i*8; ldw=128;
  } else {                                         // Wit: 5 x (ct24 kc4)
    int v=u-45056, g=v/6144, i=v%6144, ct=i>>8, kc=(i>>6)&3, lane=i&63;
    src = Wi + (size_t)g*49152 + (size_t)(kc*32 + 8*(lane>>4))*384 + ct*16 + (lane&15);
    dst = Wit + (size_t)g*49152 + i*8; ldw=384;
  }
  short8 o;
#pragma unroll
  for (int j=0;j<8;++j) o[j] = f2bf(src[(size_t)j*ldw]);
  *(short8*)dst = o;
}

// ---------------- bucket sort by gate, per level ----------------
__global__ void count_kernel(const int* __restrict__ gate, int* __restrict__ cnt){
  __shared__ int lc[GG];
  const int li = blockIdx.x >> 7;
  const int m  = ((blockIdx.x & 127) << 8) + threadIdx.x;
  if (threadIdx.x < GG) lc[threadIdx.x] = 0;
  __syncthreads();
  int g = gate[(li+1)*MM + m];
  atomicAdd(&lc[g], 1);
  __syncthreads();
  if (threadIdx.x < GG && lc[threadIdx.x] > 0)
    atomicAdd(&cnt[li*GG + threadIdx.x], lc[threadIdx.x]);
}

// offsets + fill pad slots with -1 (replaces 1MB memset node)
__global__ void offs_kernel(const int* __restrict__ cnt, int* __restrict__ off,
                            int* __restrict__ pend, int* __restrict__ sorted){
  __shared__ int se[35], sp[35];
  const int tid = threadIdx.x;
  if (tid < LL-1){
    int l = tid, o = 0;
    for (int g = 0; g < GG; ++g){
      off[l*GG+g] = o;
      int c = cnt[l*GG+g];
      pend[l*GG+g] = o + c;
      se[l*GG+g] = o + c;
      o += ((c + 127) >> 7) << 7;
      sp[l*GG+g] = o;
    }
  }
  __syncthreads();
  for (int b = 0; b < 35; ++b){
    int l = b / GG;
    for (int i = se[b] + tid; i < sp[b]; i += 256)
      sorted[l*SORT_STRIDE + i] = -1;
  }
}

__global__ void scatter_kernel(const int* __restrict__ gate, const int* __restrict__ off,
                               int* __restrict__ cur, int* __restrict__ sorted){
  __shared__ int lc[GG];
  __shared__ int base[GG];
  const int li = blockIdx.x >> 7;
  const int m  = ((blockIdx.x & 127) << 8) + threadIdx.x;
  if (threadIdx.x < GG) lc[threadIdx.x] = 0;
  __syncthreads();
  int g = gate[(li+1)*MM + m];
  int p = atomicAdd(&lc[g], 1);
  __syncthreads();
  if (threadIdx.x < GG)
    base[threadIdx.x] = atomicAdd(&cur[li*GG + threadIdx.x], lc[threadIdx.x]);
  __syncthreads();
  sorted[li*SORT_STRIDE + off[li*GG+g] + base[g] + p] = m;
}

// ---------------- hs = [s|t] @ hs_W + hs_b  (+ level-0 hf zero-fill) -------
__global__ __launch_bounds__(512,4) void hs_kernel(
    const float* __restrict__ s, const float* __restrict__ t,
    const short* __restrict__ Wt, const float* __restrict__ b,
    float* __restrict__ hs, short* __restrict__ hs_sh,
    float* __restrict__ hf, short* __restrict__ hf_sh)
{
  __shared__ __align__(16) short Xs[32768];
  const int tid=threadIdx.x, lane=tid&63, w=tid>>6;
  const int l15=lane&15, lq=lane>>4;
  const int wr=w>>2, wc=w&3;
  const int row0 = blockIdx.x*128;

  // stage X rows into fragment layout
  {
    const int r = tid>>2, p = tid&3;
    const float* srow = s + (size_t)(row0+r)*DD;
    const float* trow = t + (size_t)(row0+r)*DD;
    const int rf = r>>4, rl = r&15;
#pragma unroll
    for (int i=0;i<8;++i){
      int u = p + 4*i;
      const float* pp = (u<16) ? (srow + 8*u) : (trow + 8*(u-16));
      short8 v = pack8(*(const f32x4*)pp, *(const f32x4*)(pp+4));
      *(short8*)(Xs + ((rf*8+(u>>2))*64 + (u&3)*16 + rl)*8) = v;
    }
  }

  // level-0 hf zero-fill (replaces two memset nodes)
  if (row0 < MM){
    f32x4 zf4 = {0.f,0.f,0.f,0.f};
    short8 zs8 = {0,0,0,0,0,0,0,0};
    const size_t basei = (size_t)row0*DD;
    for (int i=tid; i<4096; i+=512) *(f32x4*)(hf + basei + i*4) = zf4;
    for (int i=tid; i<2048; i+=512) *(short8*)(hf_sh + basei + i*8) = zs8;
  }
  __syncthreads();

  f32x4 zf = {0.f,0.f,0.f,0.f};
  f32x4 acc[4][2];
#pragma unroll
  for (int rr=0;rr<4;++rr){ acc[rr][0]=zf; acc[rr][1]=zf; }

  const short* Ab = Wt + lane*8;     // frag (ct,kc) at + (ct*8+kc)*512
#pragma unroll
  for (int kc=0;kc<8;++kc){
    short8 a0 = *(const short8*)(Ab + (16*wc + kc)*512);
    short8 a1 = *(const short8*)(Ab + (16*wc + 8 + kc)*512);
#pragma unroll
    for (int rr=0;rr<4;++rr){
      short8 bx = *(const short8*)(Xs + (((4*wr+rr)*8 + kc)*64 + lane)*8);
      acc[rr][0] = MFMA16(a0, bx, acc[rr][0]);
      acc[rr][1] = MFMA16(a1, bx, acc[rr][1]);
    }
  }

  f32x4 bv0 = *(const f32x4*)(b + 32*wc + 4*lq);
  f32x4 bv1 = *(const f32x4*)(b + 32*wc + 16 + 4*lq);
#pragma unroll
  for (int rr=0;rr<4;++rr){
    int row = row0 + (4*wr+rr)*16 + l15;
#pragma unroll
    for (int q=0;q<2;++q){
      f32x4 bv = q ? bv1 : bv0;
      int col = 32*wc + 16*q + 4*lq;
      f32x4 o; short4v pk;
#pragma unroll
      for (int j=0;j<4;++j){ o[j] = acc[rr][q][j] + bv[j]; pk[j] = f2bf(o[j]); }
      *(f32x4*)(hs + (size_t)row*DD + col) = o;
      *(short4v*)(hs_sh + (size_t)row*DD + col) = pk;
    }
  }
}

// ---------------- fused per-level kernel ----------------
__global__ __launch_bounds__(512,4) void level_kernel(
    int lvl, float* __restrict__ hfg,
    const short* __restrict__ hs_sh, short* __restrict__ hf_sh,
    const int* __restrict__ fanin,
    const short* __restrict__ W1t, const short* __restrict__ W2t,
    const short* __restrict__ W3t, const short* __restrict__ Wit,
    const float* __restrict__ b1, const float* __restrict__ b2,
    const float* __restrict__ b3, const float* __restrict__ bi,
    const float* __restrict__ bh,
    const int* __restrict__ off, const int* __restrict__ pend,
    const int* __restrict__ sorted)
{
  __shared__ __align__(16) short Xs[32768];
  __shared__ int nodebuf[64];
  __shared__ int srcbuf[128];
  __shared__ int ginfo;

  const int tid=threadIdx.x, lane=tid&63, w=tid>>6;
  const int l15=lane&15, lq=lane>>4;
  const int wr=w>>2, wc=w&3;
  const int li = lvl-1;
  const int pos0 = blockIdx.x*64;

  if (tid==0){
    int g=-1;
    for (int q=0;q<GG;++q)
      if (pos0>=off[li*GG+q] && pos0<pend[li*GG+q]){ g=q; break; }
    ginfo=g;
  }
  if (tid<64) nodebuf[tid] = sorted[li*SORT_STRIDE + pos0 + tid];
  if (tid<128){
    int mg = sorted[li*SORT_STRIDE + pos0 + (tid>>1)];
    srcbuf[tid] = (mg>=0) ? li*MM + fanin[((size_t)li*MM+mg)*FF + (tid&1)] : 0;
  }
  __syncthreads();                                  // B0
  const int g = ginfo;
  if (g<0) return;                                  // block-uniform

  // gather X rows into fragment layout
  {
    const int r = tid>>2, p = tid&3;
    const int src = srcbuf[r];
    const short* hsrow = hs_sh + (size_t)src*DD;
    const short* hfrow = hf_sh + (size_t)src*DD;
    const int rf = r>>4, rl = r&15;
#pragma unroll
    for (int i=0;i<8;++i){
      int u = p + 4*i;
      short8 v = *(const short8*)((u<16) ? (hsrow + 8*u) : (hfrow + 8*(u-16)));
      *(short8*)(Xs + ((rf*8+(u>>2))*64 + (u&3)*16 + rl)*8) = v;
    }
  }
  __syncthreads();                                  // B1

  f32x4 zf = {0.f,0.f,0.f,0.f};

  // ---- GEMM1: K=256 ----
  f32x4 acc[4][2];
#pragma unroll
  for (int rr=0;rr<4;++rr){ acc[rr][0]=zf; acc[rr][1]=zf; }
  const short* A1 = W1t + (size_t)g*32768 + lane*8;
#pragma unroll
  for (int kc=0;kc<8;++kc){
    short8 a0 = *(const short8*)(A1 + (16*wc + kc)*512);
    short8 a1 = *(const short8*)(A1 + (16*wc + 8 + kc)*512);
#pragma unroll
    for (int rr=0;rr<4;++rr){
      short8 bx = *(const short8*)(Xs + (((4*wr+rr)*8 + kc)*64 + lane)*8);
      acc[rr][0] = MFMA16(a0, bx, acc[rr][0]);
      acc[rr][1] = MFMA16(a1, bx, acc[rr][1]);
    }
  }
  __syncthreads();                                  // B2: all X reads done
  {
    f32x4 bv0 = *(const f32x4*)(b1 + g*DD + 32*wc + 4*lq);
    f32x4 bv1 = *(const f32x4*)(b1 + g*DD + 32*wc + 16 + 4*lq);
#pragma unroll
    for (int rr=0;rr<4;++rr){
      int rf = 4*wr + rr;
#pragma unroll
      for (int q=0;q<2;++q){
        f32x4 bv = q ? bv1 : bv0;
        short4v pk;
#pragma unroll
        for (int j=0;j<4;++j) pk[j] = f2bf(fmaxf(acc[rr][q][j] + bv[j], 0.f));
        *(short4v*)(Xs + ((rf*4 + wc)*64 + (2*q + (lq>>1))*16 + l15)*8 + 4*(lq&1)) = pk;
      }
    }
  }
  __syncthreads();                                  // B3: H1 ready

  // ---- GEMM2: K=128 ----
  f32x4 acc2[4][2];
#pragma unroll
  for (int rr=0;rr<4;++rr){ acc2[rr][0]=zf; acc2[rr][1]=zf; }
  const short* A2 = W2t + (size_t)g*16384 + lane*8;
#pragma unroll
  for (int kc=0;kc<4;++kc){
    short8 a0 = *(const short8*)(A2 + (8*wc + kc)*512);
    short8 a1 = *(const short8*)(A2 + (8*wc + 4 + kc)*512);
#pragma unroll
    for (int rr=0;rr<4;++rr){
      short8 bx = *(const short8*)(Xs + (((4*wr+rr)*4 + kc)*64 + lane)*8);
      acc2[rr][0] = MFMA16(a0, bx, acc2[rr][0]);
      acc2[rr][1] = MFMA16(a1, bx, acc2[rr][1]);
    }
  }
  {
    f32x4 bv0 = *(const f32x4*)(b2 + g*DD + 32*wc + 4*lq);
    f32x4 bv1 = *(const f32x4*)(b2 + g*DD + 32*wc + 16 + 4*lq);
#pragma unroll
    for (int rr=0;rr<4;++rr){
      int rf = 4*wr + rr;
#pragma unroll
      for (int q=0;q<2;++q){
        f32x4 bv = q ? bv1 : bv0;
        short4v pk;
#pragma unroll
        for (int j=0;j<4;++j) pk[j] = f2bf(fmaxf(acc2[rr][q][j] + bv[j], 0.f));
        *(short4v*)(Xs + 16384 + ((rf*4 + wc)*64 + (2*q + (lq>>1))*16 + l15)*8 + 4*(lq&1)) = pk;
      }
    }
  }
  __syncthreads();                                  // B4: H2 ready

  // ---- GEMM3: K=128 ----
  f32x4 acc3[4][2];
#pragma unroll
  for (int rr=0;rr<4;++rr){ acc3[rr][0]=zf; acc3[rr][1]=zf; }
  const short* A3 = W3t + (size_t)g*16384 + lane*8;
#pragma unroll
  for (int kc=0;kc<4;++kc){
    short8 a0 = *(const short8*)(A3 + (8*wc + kc)*512);
    short8 a1 = *(const short8*)(A3 + (8*wc + 4 + kc)*512);
#pragma unroll
    for (int rr=0;rr<4;++rr){
      short8 bx = *(const short8*)(Xs + 16384 + (((4*wr+rr)*4 + kc)*64 + lane)*8);
      acc3[rr][0] = MFMA16(a0, bx, acc3[rr][0]);
      acc3[rr][1] = MFMA16(a1, bx, acc3[rr][1]);
    }
  }
  // pair-sum over F -> msg into Xs[0:8192]
  {
    f32x4 bv0 = *(const f32x4*)(b3 + g*DD + 32*wc + 4*lq);
    f32x4 bv1 = *(const f32x4*)(b3 + g*DD + 32*wc + 16 + 4*lq);
#pragma unroll
    for (int rr=0;rr<4;++rr){
#pragma unroll
      for (int q=0;q<2;++q){
        f32x4 bv = q ? bv1 : bv0;
        f32x4 mv;
#pragma unroll
        for (int j=0;j<4;++j){
          float v = acc3[rr][q][j];
          mv[j] = v + __shfl_xor(v, 1) + 2.f*bv[j];
        }
        if ((l15 & 1) == 0){
          int n = (4*wr+rr)*8 + (l15>>1);
          short4v pk;
#pragma unroll
          for (int j=0;j<4;++j) pk[j] = f2bf(mv[j]);
          *(short4v*)(Xs + (((n>>4)*4 + wc)*64 + (2*q + (lq>>1))*16 + (n&15))*8 + 4*(lq&1)) = pk;
        }
      }
    }
  }
  __syncthreads();                                  // B5: msg ready

  // ---- GRU: gi = msg(64x128) @ Wi[g]; h==0 so gh==bh ----
  f32x4 gr[4], gz[4], gn[4];
#pragma unroll
  for (int rfm=0;rfm<4;++rfm){ gr[rfm]=zf; gz[rfm]=zf; gn[rfm]=zf; }
  const short* AW = Wit + (size_t)g*49152 + lane*8;
#pragma unroll
  for (int kc=0;kc<4;++kc){
    short8 aR = *(const short8*)(AW + ((w)*4 + kc)*512);
    short8 aZ = *(const short8*)(AW + ((8+w)*4 + kc)*512);
    short8 aN = *(const short8*)(AW + ((16+w)*4 + kc)*512);
#pragma unroll
    for (int rfm=0;rfm<4;++rfm){
      short8 bm = *(const short8*)(Xs + ((rfm*4 + kc)*64 + lane)*8);
      gr[rfm] = MFMA16(aR, bm, gr[rfm]);
      gz[rfm] = MFMA16(aZ, bm, gz[rfm]);
      gn[rfm] = MFMA16(aN, bm, gn[rfm]);
    }
  }

  const int lo = lvl*MM;
  f32x4 biR = *(const f32x4*)(bi + g*384 + 16*w + 4*lq);
  f32x4 biZ = *(const f32x4*)(bi + g*384 + 128 + 16*w + 4*lq);
  f32x4 biN = *(const f32x4*)(bi + g*384 + 256 + 16*w + 4*lq);
  f32x4 bhR = *(const f32x4*)(bh + g*384 + 16*w + 4*lq);
  f32x4 bhZ = *(const f32x4*)(bh + g*384 + 128 + 16*w + 4*lq);
  f32x4 bhN = *(const f32x4*)(bh + g*384 + 256 + 16*w + 4*lq);
#pragma unroll
  for (int rfm=0;rfm<4;++rfm){
    int m = nodebuf[rfm*16 + l15];
    if (m < 0) continue;
    f32x4 o; short4v pk;
#pragma unroll
    for (int j=0;j<4;++j){
      float xr = gr[rfm][j] + biR[j] + bhR[j];
      float xz = gz[rfm][j] + biZ[j] + bhZ[j];
      float r_ = 1.f/(1.f + __expf(-xr));
      float z_ = 1.f/(1.f + __expf(-xz));
      float xn = gn[rfm][j] + biN[j] + r_*bhN[j];
      float n_ = 2.f/(1.f + __expf(-2.f*xn)) - 1.f;
      o[j] = (1.f - z_)*n_;
      pk[j] = f2bf(o[j]);
    }
    int col = 16*w + 4*lq;
    *(f32x4*)(hfg + (size_t)(lo + m)*DD + col) = o;
    *(short4v*)(hf_sh + (size_t)(lo + m)*DD + col) = pk;
  }
}

extern "C" void kernel_launch(void* const* d_in, const int* in_sizes, int n_in,
                              void* d_out, int out_size, void* d_ws, size_t ws_size,
                              hipStream_t stream)
{
  const float* s    = (const float*)d_in[0];
  const float* t    = (const float*)d_in[1];
  const int*   gate = (const int*)d_in[2];
  const int*   fanin= (const int*)d_in[3];
  const float* hs_W = (const float*)d_in[4];
  const float* hs_b = (const float*)d_in[5];
  const float* W1   = (const float*)d_in[6];
  const float* b1   = (const float*)d_in[7];
  const float* W2   = (const float*)d_in[8];
  const float* b2   = (const float*)d_in[9];
  const float* W3   = (const float*)d_in[10];
  const float* b3   = (const float*)d_in[11];
  const float* Wi   = (const float*)d_in[12];
  // d_in[13] = gru_Wh: unused (hidden state is exactly zero)
  const float* bi   = (const float*)d_in[14];
  const float* bh   = (const float*)d_in[15];

  float* hs = (float*)d_out;
  float* hf = hs + (size_t)NN*DD;

  int* cnt    = (int*)d_ws;        // [7][5] ; cur right after
  int* cur    = cnt + 35;
  int* off    = cnt + 70;
  int* pendv  = cnt + 105;
  int* sorted = cnt + 256;         // 7*SORT_STRIDE ints, < 1 MB

  short* wbase = (short*)((char*)d_ws + (1<<20));
  short* hsWt = wbase;             // 4096*8
  short* W1t  = wbase + 32768;     // 5*32768
  short* W2t  = wbase + 196608;    // 5*16384
  short* W3t  = wbase + 278528;    // 5*16384
  short* Wit  = wbase + 360448;    // 5*49152

  short* hs_sh = (short*)((char*)d_ws + (size_t)(8<<20));   // [N][128] bf16
  short* hf_sh = hs_sh + (size_t)NN*DD;                      // [N][128] bf16

  prep_kernel<<<296, 256, 0, stream>>>(hs_W, W1, W2, W3, Wi,
                                       hsWt, W1t, W2t, W3t, Wit, cnt);
  count_kernel<<<896, 256, 0, stream>>>(gate, cnt);
  offs_kernel<<<1, 256, 0, stream>>>(cnt, off, pendv, sorted);
  scatter_kernel<<<896, 256, 0, stream>>>(gate, off, cur, sorted);
  hs_kernel<<<NN/128, 512, 0, stream>>>(s, t, hsWt, hs_b, hs, hs_sh, hf, hf_sh);
  for (int lvl = 1; lvl < LL; ++lvl){
    level_kernel<<<SORT_STRIDE/64, 512, 0, stream>>>(lvl, hf,
        hs_sh, hf_sh, fanin, W1t, W2t, W3t, Wit,
        b1, b2, b3, bi, bh, off, pendv, sorted);
  }
}

// Round 6
// 397.188 us; speedup vs baseline: 2.4647x; 1.0427x over previous
//
#include <hip/hip_runtime.h>
#include <hip/hip_bf16.h>

#define DD 128
#define LL 8
#define MM 32768
#define NN (LL*MM)
#define GG 5
#define FF 2
#define SORT_STRIDE 33408   // 32768 + headroom (>= 5*31 pad)

typedef __attribute__((ext_vector_type(8))) short short8;
typedef __attribute__((ext_vector_type(4))) short short4v;
typedef __attribute__((ext_vector_type(4))) float f32x4;

#define MFMA16(a,b,c) __builtin_amdgcn_mfma_f32_16x16x32_bf16((a),(b),(c),0,0,0)

__device__ __forceinline__ short f2bf(float x){
  __hip_bfloat16 h = __float2bfloat16(x);
  return *reinterpret_cast<short*>(&h);
}

__device__ __forceinline__ short8 pack8(f32x4 a, f32x4 b){
  short8 r;
  r[0]=f2bf(a[0]); r[1]=f2bf(a[1]); r[2]=f2bf(a[2]); r[3]=f2bf(a[3]);
  r[4]=f2bf(b[0]); r[5]=f2bf(b[1]); r[6]=f2bf(b[2]); r[7]=f2bf(b[3]);
  return r;
}

// ---------------- one-time weight convert to fragment-contiguous bf16 ------
// Layout per tensor: [g][ct][kc][lane][8]  (ct = 16-col tile, kc = 32-k tile)
// value[j] = W[k = kc*32 + 8*(lane>>4) + j][col = ct*16 + (lane&15)]
__global__ void prep_kernel(const float* __restrict__ hs_W, const float* __restrict__ W1,
                            const float* __restrict__ W2, const float* __restrict__ W3,
                            const float* __restrict__ Wi,
                            short* __restrict__ hsWt, short* __restrict__ W1t,
                            short* __restrict__ W2t, short* __restrict__ W3t,
                            short* __restrict__ Wit, int* __restrict__ cntcur)
{
  if (blockIdx.x == 0 && threadIdx.x < 70) cntcur[threadIdx.x] = 0;  // cnt[35]+cur[35]
  int u = blockIdx.x*256 + threadIdx.x;   // 75776 units of 8 k-elems
  const float* src; short* dst; int ldw;
  if (u < 4096){                                   // hsWt: ct8 kc8
    int i=u, ct=i>>9, kc=(i>>6)&7, lane=i&63;
    src = hs_W + (size_t)(kc*32 + 8*(lane>>4))*128 + ct*16 + (lane&15);
    dst = hsWt + (size_t)i*8; ldw=128;
  } else if (u < 24576){                           // W1t: 5 x (ct8 kc8)
    int v=u-4096, g=v>>12, i=v&4095, ct=i>>9, kc=(i>>6)&7, lane=i&63;
    src = W1 + (size_t)g*32768 + (size_t)(kc*32 + 8*(lane>>4))*128 + ct*16 + (lane&15);
    dst = W1t + (size_t)g*32768 + i*8; ldw=128;
  } else if (u < 34816){                           // W2t: 5 x (ct8 kc4)
    int v=u-24576, g=v>>11, i=v&2047, ct=i>>8, kc=(i>>6)&3, lane=i&63;
    src = W2 + (size_t)g*16384 + (size_t)(kc*32 + 8*(lane>>4))*128 + ct*16 + (lane&15);
    dst = W2t + (size_t)g*16384 + i*8; ldw=128;
  } else if (u < 45056){                           // W3t: 5 x (ct8 kc4)
    int v=u-34816, g=v>>11, i=v&2047, ct=i>>8, kc=(i>>6)&3, lane=i&63;
    src = W3 + (size_t)g*16384 + (size_t)(kc*32 + 8*(lane>>4))*128 + ct*16 + (lane&15);
    dst = W3t + (size_t)g*16384 + i*8; ldw=128;
  } else {                                         // Wit: 5 x (ct24 kc4)
    int v=u-45056, g=v/6144, i=v%6144, ct=i>>8, kc=(i>>6)&3, lane=i&63;
    src = Wi + (size_t)g*49152 + (size_t)(kc*32 + 8*(lane>>4))*384 + ct*16 + (lane&15);
    dst = Wit + (size_t)g*49152 + i*8; ldw=384;
  }
  short8 o;
#pragma unroll
  for (int j=0;j<8;++j) o[j] = f2bf(src[(size_t)j*ldw]);
  *(short8*)dst = o;
}

// ---------------- bucket sort by gate, per level ----------------
__global__ void count_kernel(const int* __restrict__ gate, int* __restrict__ cnt){
  __shared__ int lc[GG];
  const int li = blockIdx.x >> 7;
  const int m  = ((blockIdx.x & 127) << 8) + threadIdx.x;
  if (threadIdx.x < GG) lc[threadIdx.x] = 0;
  __syncthreads();
  int g = gate[(li+1)*MM + m];
  atomicAdd(&lc[g], 1);
  __syncthreads();
  if (threadIdx.x < GG && lc[threadIdx.x] > 0)
    atomicAdd(&cnt[li*GG + threadIdx.x], lc[threadIdx.x]);
}

// offsets (pad 32) + fill pad slots with -1
__global__ void offs_kernel(const int* __restrict__ cnt, int* __restrict__ off,
                            int* __restrict__ pend, int* __restrict__ sorted){
  __shared__ int se[35], sp[35];
  const int tid = threadIdx.x;
  if (tid < LL-1){
    int l = tid, o = 0;
    for (int g = 0; g < GG; ++g){
      off[l*GG+g] = o;
      int c = cnt[l*GG+g];
      pend[l*GG+g] = o + c;
      se[l*GG+g] = o + c;
      o += ((c + 31) >> 5) << 5;          // pad each bucket to 32
      sp[l*GG+g] = o;
    }
  }
  __syncthreads();
  for (int b = 0; b < 35; ++b){
    int l = b / GG;
    for (int i = se[b] + tid; i < sp[b]; i += 256)
      sorted[l*SORT_STRIDE + i] = -1;
  }
}

__global__ void scatter_kernel(const int* __restrict__ gate, const int* __restrict__ off,
                               int* __restrict__ cur, int* __restrict__ sorted){
  __shared__ int lc[GG];
  __shared__ int base[GG];
  const int li = blockIdx.x >> 7;
  const int m  = ((blockIdx.x & 127) << 8) + threadIdx.x;
  if (threadIdx.x < GG) lc[threadIdx.x] = 0;
  __syncthreads();
  int g = gate[(li+1)*MM + m];
  int p = atomicAdd(&lc[g], 1);
  __syncthreads();
  if (threadIdx.x < GG)
    base[threadIdx.x] = atomicAdd(&cur[li*GG + threadIdx.x], lc[threadIdx.x]);
  __syncthreads();
  sorted[li*SORT_STRIDE + off[li*GG+g] + base[g] + p] = m;
}

// ---------------- hs = [s|t] @ hs_W + hs_b  (+ level-0 hf zero-fill) -------
__global__ __launch_bounds__(512,4) void hs_kernel(
    const float* __restrict__ s, const float* __restrict__ t,
    const short* __restrict__ Wt, const float* __restrict__ b,
    float* __restrict__ hs, short* __restrict__ hs_sh,
    float* __restrict__ hf, short* __restrict__ hf_sh)
{
  __shared__ __align__(16) short Xs[32768];
  const int tid=threadIdx.x, lane=tid&63, w=tid>>6;
  const int l15=lane&15, lq=lane>>4;
  const int wr=w>>2, wc=w&3;
  const int row0 = blockIdx.x*128;

  // stage X rows into fragment layout
  {
    const int r = tid>>2, p = tid&3;
    const float* srow = s + (size_t)(row0+r)*DD;
    const float* trow = t + (size_t)(row0+r)*DD;
    const int rf = r>>4, rl = r&15;
#pragma unroll
    for (int i=0;i<8;++i){
      int u = p + 4*i;
      const float* pp = (u<16) ? (srow + 8*u) : (trow + 8*(u-16));
      short8 v = pack8(*(const f32x4*)pp, *(const f32x4*)(pp+4));
      *(short8*)(Xs + ((rf*8+(u>>2))*64 + (u&3)*16 + rl)*8) = v;
    }
  }

  // level-0 hf zero-fill (replaces memset nodes)
  if (row0 < MM){
    f32x4 zf4 = {0.f,0.f,0.f,0.f};
    short8 zs8 = {0,0,0,0,0,0,0,0};
    const size_t basei = (size_t)row0*DD;
    for (int i=tid; i<4096; i+=512) *(f32x4*)(hf + basei + i*4) = zf4;
    for (int i=tid; i<2048; i+=512) *(short8*)(hf_sh + basei + i*8) = zs8;
  }
  __syncthreads();

  f32x4 zf = {0.f,0.f,0.f,0.f};
  f32x4 acc[4][2];
#pragma unroll
  for (int rr=0;rr<4;++rr){ acc[rr][0]=zf; acc[rr][1]=zf; }

  const short* Ab = Wt + lane*8;     // frag (ct,kc) at + (ct*8+kc)*512
#pragma unroll
  for (int kc=0;kc<8;++kc){
    short8 a0 = *(const short8*)(Ab + (16*wc + kc)*512);
    short8 a1 = *(const short8*)(Ab + (16*wc + 8 + kc)*512);
#pragma unroll
    for (int rr=0;rr<4;++rr){
      short8 bx = *(const short8*)(Xs + (((4*wr+rr)*8 + kc)*64 + lane)*8);
      acc[rr][0] = MFMA16(a0, bx, acc[rr][0]);
      acc[rr][1] = MFMA16(a1, bx, acc[rr][1]);
    }
  }

  f32x4 bv0 = *(const f32x4*)(b + 32*wc + 4*lq);
  f32x4 bv1 = *(const f32x4*)(b + 32*wc + 16 + 4*lq);
#pragma unroll
  for (int rr=0;rr<4;++rr){
    int row = row0 + (4*wr+rr)*16 + l15;
#pragma unroll
    for (int q=0;q<2;++q){
      f32x4 bv = q ? bv1 : bv0;
      int col = 32*wc + 16*q + 4*lq;
      f32x4 o; short4v pk;
#pragma unroll
      for (int j=0;j<4;++j){ o[j] = acc[rr][q][j] + bv[j]; pk[j] = f2bf(o[j]); }
      *(f32x4*)(hs + (size_t)row*DD + col) = o;
      *(short4v*)(hs_sh + (size_t)row*DD + col) = pk;
    }
  }
}

// ---------------- fused per-level kernel: 32 nodes/block, 4 waves ----------
// Wave w owns cols 32w..32w+31 (ct = 2w, 2w+1) of all 64 rows.
// LDS: X 32KB; H1 overlays X[0:8192] shorts; H2 at [8192:16384); msg [0:4096).
__global__ __launch_bounds__(256,4) void level_kernel(
    int lvl, float* __restrict__ hfg,
    const short* __restrict__ hs_sh, short* __restrict__ hf_sh,
    const int* __restrict__ fanin,
    const short* __restrict__ W1t, const short* __restrict__ W2t,
    const short* __restrict__ W3t, const short* __restrict__ Wit,
    const float* __restrict__ b1, const float* __restrict__ b2,
    const float* __restrict__ b3, const float* __restrict__ bi,
    const float* __restrict__ bh,
    const int* __restrict__ off, const int* __restrict__ pend,
    const int* __restrict__ sorted)
{
  __shared__ __align__(16) short Xs[16384];
  __shared__ int nodebuf[32];
  __shared__ int srcbuf[64];
  __shared__ int ginfo;

  const int tid=threadIdx.x, lane=tid&63, w=tid>>6;  // w = 0..3
  const int l15=lane&15, lq=lane>>4;
  const int li = lvl-1;
  const int pos0 = blockIdx.x*32;

  if (tid==0){
    int g=-1;
    for (int q=0;q<GG;++q)
      if (pos0>=off[li*GG+q] && pos0<pend[li*GG+q]){ g=q; break; }
    ginfo=g;
  }
  if (tid<32) nodebuf[tid] = sorted[li*SORT_STRIDE + pos0 + tid];
  if (tid<64){
    int mg = sorted[li*SORT_STRIDE + pos0 + (tid>>1)];
    srcbuf[tid] = (mg>=0) ? li*MM + fanin[((size_t)li*MM+mg)*FF + (tid&1)] : 0;
  }
  __syncthreads();                                  // B0
  const int g = ginfo;
  if (g<0) return;                                  // block-uniform

  // gather X rows into fragment layout (64 rows x 32 units / 256 thr)
  {
    const int r = tid>>2, p = tid&3;
    const int src = srcbuf[r];
    const short* hsrow = hs_sh + (size_t)src*DD;
    const short* hfrow = hf_sh + (size_t)src*DD;
    const int rf = r>>4, rl = r&15;
#pragma unroll
    for (int i=0;i<8;++i){
      int u = p + 4*i;
      short8 v = *(const short8*)((u<16) ? (hsrow + 8*u) : (hfrow + 8*(u-16)));
      *(short8*)(Xs + ((rf*8+(u>>2))*64 + (u&3)*16 + rl)*8) = v;
    }
  }
  __syncthreads();                                  // B1

  f32x4 zf = {0.f,0.f,0.f,0.f};

  // ---- GEMM1: K=256 ----
  f32x4 acc[4][2];
#pragma unroll
  for (int rr=0;rr<4;++rr){ acc[rr][0]=zf; acc[rr][1]=zf; }
  const short* A1 = W1t + (size_t)g*32768 + lane*8;
#pragma unroll
  for (int kc=0;kc<8;++kc){
    short8 a0 = *(const short8*)(A1 + (16*w + kc)*512);
    short8 a1 = *(const short8*)(A1 + (16*w + 8 + kc)*512);
#pragma unroll
    for (int rr=0;rr<4;++rr){
      short8 bx = *(const short8*)(Xs + ((rr*8 + kc)*64 + lane)*8);
      acc[rr][0] = MFMA16(a0, bx, acc[rr][0]);
      acc[rr][1] = MFMA16(a1, bx, acc[rr][1]);
    }
  }
  __syncthreads();                                  // B2: all X reads done
  {
    f32x4 bv0 = *(const f32x4*)(b1 + g*DD + 32*w + 4*lq);
    f32x4 bv1 = *(const f32x4*)(b1 + g*DD + 32*w + 16 + 4*lq);
#pragma unroll
    for (int rr=0;rr<4;++rr){
#pragma unroll
      for (int q=0;q<2;++q){
        f32x4 bv = q ? bv1 : bv0;
        short4v pk;
#pragma unroll
        for (int j=0;j<4;++j) pk[j] = f2bf(fmaxf(acc[rr][q][j] + bv[j], 0.f));
        *(short4v*)(Xs + ((rr*4 + w)*64 + (2*q + (lq>>1))*16 + l15)*8 + 4*(lq&1)) = pk;
      }
    }
  }
  __syncthreads();                                  // B3: H1 ready

  // ---- GEMM2: K=128, B from H1 (Xs[0:8192]) ----
  f32x4 acc2[4][2];
#pragma unroll
  for (int rr=0;rr<4;++rr){ acc2[rr][0]=zf; acc2[rr][1]=zf; }
  const short* A2 = W2t + (size_t)g*16384 + lane*8;
#pragma unroll
  for (int kc=0;kc<4;++kc){
    short8 a0 = *(const short8*)(A2 + (8*w + kc)*512);
    short8 a1 = *(const short8*)(A2 + (8*w + 4 + kc)*512);
#pragma unroll
    for (int rr=0;rr<4;++rr){
      short8 bx = *(const short8*)(Xs + ((rr*4 + kc)*64 + lane)*8);
      acc2[rr][0] = MFMA16(a0, bx, acc2[rr][0]);
      acc2[rr][1] = MFMA16(a1, bx, acc2[rr][1]);
    }
  }
  // H2 -> Xs[8192:16384) (disjoint from H1; region dead since B2)
  {
    f32x4 bv0 = *(const f32x4*)(b2 + g*DD + 32*w + 4*lq);
    f32x4 bv1 = *(const f32x4*)(b2 + g*DD + 32*w + 16 + 4*lq);
#pragma unroll
    for (int rr=0;rr<4;++rr){
#pragma unroll
      for (int q=0;q<2;++q){
        f32x4 bv = q ? bv1 : bv0;
        short4v pk;
#pragma unroll
        for (int j=0;j<4;++j) pk[j] = f2bf(fmaxf(acc2[rr][q][j] + bv[j], 0.f));
        *(short4v*)(Xs + 8192 + ((rr*4 + w)*64 + (2*q + (lq>>1))*16 + l15)*8 + 4*(lq&1)) = pk;
      }
    }
  }
  __syncthreads();                                  // B4: H2 ready, H1 reads done

  // ---- GEMM3: K=128, B from H2 ----
  f32x4 acc3[4][2];
#pragma unroll
  for (int rr=0;rr<4;++rr){ acc3[rr][0]=zf; acc3[rr][1]=zf; }
  const short* A3 = W3t + (size_t)g*16384 + lane*8;
#pragma unroll
  for (int kc=0;kc<4;++kc){
    short8 a0 = *(const short8*)(A3 + (8*w + kc)*512);
    short8 a1 = *(const short8*)(A3 + (8*w + 4 + kc)*512);
#pragma unroll
    for (int rr=0;rr<4;++rr){
      short8 bx = *(const short8*)(Xs + 8192 + ((rr*4 + kc)*64 + lane)*8);
      acc3[rr][0] = MFMA16(a0, bx, acc3[rr][0]);
      acc3[rr][1] = MFMA16(a1, bx, acc3[rr][1]);
    }
  }
  // pair-sum over F -> msg into Xs[0:4096)
  {
    f32x4 bv0 = *(const f32x4*)(b3 + g*DD + 32*w + 4*lq);
    f32x4 bv1 = *(const f32x4*)(b3 + g*DD + 32*w + 16 + 4*lq);
#pragma unroll
    for (int rr=0;rr<4;++rr){
#pragma unroll
      for (int q=0;q<2;++q){
        f32x4 bv = q ? bv1 : bv0;
        f32x4 mv;
#pragma unroll
        for (int j=0;j<4;++j){
          float v = acc3[rr][q][j];
          mv[j] = v + __shfl_xor(v, 1) + 2.f*bv[j];
        }
        if ((l15 & 1) == 0){
          int n = rr*8 + (l15>>1);                 // node 0..31
          short4v pk;
#pragma unroll
          for (int j=0;j<4;++j) pk[j] = f2bf(mv[j]);
          *(short4v*)(Xs + (((n>>4)*4 + w)*64 + (2*q + (lq>>1))*16 + (n&15))*8 + 4*(lq&1)) = pk;
        }
      }
    }
  }
  __syncthreads();                                  // B5: msg ready

  // ---- GRU: gi = msg(32x128) @ Wi[g]; h==0 so gh==bh ----
  f32x4 gr[2][2], gz[2][2], gn[2][2];
#pragma unroll
  for (int rfm=0;rfm<2;++rfm)
#pragma unroll
    for (int q=0;q<2;++q){ gr[rfm][q]=zf; gz[rfm][q]=zf; gn[rfm][q]=zf; }
  const short* AW = Wit + (size_t)g*49152 + lane*8;
#pragma unroll
  for (int kc=0;kc<4;++kc){
    short8 aR0 = *(const short8*)(AW + (8*w + kc)*512);
    short8 aR1 = *(const short8*)(AW + (8*w + 4 + kc)*512);
    short8 aZ0 = *(const short8*)(AW + 16384 + (8*w + kc)*512);
    short8 aZ1 = *(const short8*)(AW + 16384 + (8*w + 4 + kc)*512);
    short8 aN0 = *(const short8*)(AW + 32768 + (8*w + kc)*512);
    short8 aN1 = *(const short8*)(AW + 32768 + (8*w + 4 + kc)*512);
#pragma unroll
    for (int rfm=0;rfm<2;++rfm){
      short8 bm = *(const short8*)(Xs + ((rfm*4 + kc)*64 + lane)*8);
      gr[rfm][0] = MFMA16(aR0, bm, gr[rfm][0]);
      gr[rfm][1] = MFMA16(aR1, bm, gr[rfm][1]);
      gz[rfm][0] = MFMA16(aZ0, bm, gz[rfm][0]);
      gz[rfm][1] = MFMA16(aZ1, bm, gz[rfm][1]);
      gn[rfm][0] = MFMA16(aN0, bm, gn[rfm][0]);
      gn[rfm][1] = MFMA16(aN1, bm, gn[rfm][1]);
    }
  }

  const int lo = lvl*MM;
#pragma unroll
  for (int q=0;q<2;++q){
    int col = 32*w + 16*q + 4*lq;
    f32x4 biR = *(const f32x4*)(bi + g*384 + col);
    f32x4 biZ = *(const f32x4*)(bi + g*384 + 128 + col);
    f32x4 biN = *(const f32x4*)(bi + g*384 + 256 + col);
    f32x4 bhR = *(const f32x4*)(bh + g*384 + col);
    f32x4 bhZ = *(const f32x4*)(bh + g*384 + 128 + col);
    f32x4 bhN = *(const f32x4*)(bh + g*384 + 256 + col);
#pragma unroll
    for (int rfm=0;rfm<2;++rfm){
      int m = nodebuf[rfm*16 + l15];
      if (m < 0) continue;
      f32x4 o; short4v pk;
#pragma unroll
      for (int j=0;j<4;++j){
        float xr = gr[rfm][q][j] + biR[j] + bhR[j];
        float xz = gz[rfm][q][j] + biZ[j] + bhZ[j];
        float r_ = 1.f/(1.f + __expf(-xr));
        float z_ = 1.f/(1.f + __expf(-xz));
        float xn = gn[rfm][q][j] + biN[j] + r_*bhN[j];
        float n_ = 2.f/(1.f + __expf(-2.f*xn)) - 1.f;
        o[j] = (1.f - z_)*n_;
        pk[j] = f2bf(o[j]);
      }
      *(f32x4*)(hfg + (size_t)(lo + m)*DD + col) = o;
      *(short4v*)(hf_sh + (size_t)(lo + m)*DD + col) = pk;
    }
  }
}

extern "C" void kernel_launch(void* const* d_in, const int* in_sizes, int n_in,
                              void* d_out, int out_size, void* d_ws, size_t ws_size,
                              hipStream_t stream)
{
  const float* s    = (const float*)d_in[0];
  const float* t    = (const float*)d_in[1];
  const int*   gate = (const int*)d_in[2];
  const int*   fanin= (const int*)d_in[3];
  const float* hs_W = (const float*)d_in[4];
  const float* hs_b = (const float*)d_in[5];
  const float* W1   = (const float*)d_in[6];
  const float* b1   = (const float*)d_in[7];
  const float* W2   = (const float*)d_in[8];
  const float* b2   = (const float*)d_in[9];
  const float* W3   = (const float*)d_in[10];
  const float* b3   = (const float*)d_in[11];
  const float* Wi   = (const float*)d_in[12];
  // d_in[13] = gru_Wh: unused (hidden state is exactly zero)
  const float* bi   = (const float*)d_in[14];
  const float* bh   = (const float*)d_in[15];

  float* hs = (float*)d_out;
  float* hf = hs + (size_t)NN*DD;

  int* cnt    = (int*)d_ws;        // [7][5] ; cur right after
  int* cur    = cnt + 35;
  int* off    = cnt + 70;
  int* pendv  = cnt + 105;
  int* sorted = cnt + 256;         // 7*SORT_STRIDE ints, < 1 MB

  short* wbase = (short*)((char*)d_ws + (1<<20));
  short* hsWt = wbase;             // 4096*8
  short* W1t  = wbase + 32768;     // 5*32768
  short* W2t  = wbase + 196608;    // 5*16384
  short* W3t  = wbase + 278528;    // 5*16384
  short* Wit  = wbase + 360448;    // 5*49152

  short* hs_sh = (short*)((char*)d_ws + (size_t)(8<<20));   // [N][128] bf16
  short* hf_sh = hs_sh + (size_t)NN*DD;                      // [N][128] bf16

  prep_kernel<<<296, 256, 0, stream>>>(hs_W, W1, W2, W3, Wi,
                                       hsWt, W1t, W2t, W3t, Wit, cnt);
  count_kernel<<<896, 256, 0, stream>>>(gate, cnt);
  offs_kernel<<<1, 256, 0, stream>>>(cnt, off, pendv, sorted);
  scatter_kernel<<<896, 256, 0, stream>>>(gate, off, cur, sorted);
  hs_kernel<<<NN/128, 512, 0, stream>>>(s, t, hsWt, hs_b, hs, hs_sh, hf, hf_sh);
  for (int lvl = 1; lvl < LL; ++lvl){
    level_kernel<<<SORT_STRIDE/32, 256, 0, stream>>>(lvl, hf,
        hs_sh, hf_sh, fanin, W1t, W2t, W3t, Wit,
        b1, b2, b3, bi, bh, off, pendv, sorted);
  }
}